// Round 2
// baseline (125.882 us; speedup 1.0000x reference)
//
#include <hip/hip_runtime.h>
#include <hip/hip_bf16.h>
#include <stdint.h>

#define NB 8
#define LQ 256
#define LK 512
#define NH 64
// 2*log2(e): folded into projections so tanh(x) = 1 - 2/(1+exp2(SCALE*x_sum))
#define SCALE 2.8853900817779268f
#define L2E 1.4426950408889634f

#define QP_ELEMS (NB*LQ*NH)     // 131072 f32
#define KP_ELEMS (NB*LK*NH)     // 262144 f32

extern "C" __device__ float __ocml_exp2_f32(float);
static __device__ __forceinline__ float fexp2(float x) {
#if __has_builtin(__builtin_amdgcn_exp2f)
  return __builtin_amdgcn_exp2f(x);
#else
  return __ocml_exp2_f32(x);
#endif
}
static __device__ __forceinline__ float frcp(float x) {
  return __builtin_amdgcn_rcpf(x);
}
static __device__ __forceinline__ uint16_t f2bf(float f) {
  uint32_t u = __float_as_uint(f);
  uint32_t r = (u + 0x7FFFu + ((u >> 16) & 1u)) >> 16;  // RNE
  return (uint16_t)r;
}

// blocks 0..127:   q-projection  (64 row-tiles of 32 x 2 h-halves) -> qp[row][h] (scaled)
// blocks 128..383: k-projection  (128 row-tiles of 32 x 2 h-halves)-> kp[row][h] (scaled)
// blocks 384..447: values f32 -> bf16
__global__ __launch_bounds__(256) void proj_kernel(
    const float* __restrict__ queries, const float* __restrict__ keys,
    const float* __restrict__ values,
    const float* __restrict__ Wq, const float* __restrict__ Wk,
    float* __restrict__ qp, float* __restrict__ kp, uint16_t* __restrict__ vbf)
{
  __shared__ float Wt[256][36];  // [d][h_local], pad to 36 to break store conflicts
  const int blk = blockIdx.x;
  const int t = threadIdx.x;

  if (blk >= 384) {
    // convert values (1,048,576 f32) to bf16; 64 blocks * 256 thr * 16 * float4
    int base = (blk - 384) * 16384 + t * 4;
#pragma unroll
    for (int it = 0; it < 16; ++it) {
      int idx = base + it * 1024;
      float4 v = *(const float4*)(values + idx);
      uint32_t lo = (uint32_t)f2bf(v.x) | ((uint32_t)f2bf(v.y) << 16);
      uint32_t hi = (uint32_t)f2bf(v.z) | ((uint32_t)f2bf(v.w) << 16);
      uint2 pk = {lo, hi};
      *(uint2*)(vbf + idx) = pk;
    }
    return;
  }

  const bool isQ = (blk < 128);
  const int sub = isQ ? blk : (blk - 128);
  const int tile = sub >> 1;
  const int hh = (sub & 1) * 32;
  const int rowbase = tile * 32;
  const float* __restrict__ X = isQ ? queries : keys;
  const float* __restrict__ W = isQ ? Wq : Wk;
  float* __restrict__ P = isQ ? qp : kp;

  // stage W[hh..hh+31][0..255] transposed into Wt[d][hl]
#pragma unroll 4
  for (int it = 0; it < 32; ++it) {
    Wt[t][it] = W[(hh + it) * 256 + t];
  }
  __syncthreads();

  const int ty = t >> 4;          // 0..15 -> 2 rows each
  const int tx = t & 15;          // 0..15 -> 2 h each
  float acc[2][2];
  acc[0][0] = acc[0][1] = acc[1][0] = acc[1][1] = 0.f;

  const float* xr0 = X + (rowbase + ty * 2 + 0) * 256;
  const float* xr1 = X + (rowbase + ty * 2 + 1) * 256;

#pragma unroll 4
  for (int d4 = 0; d4 < 64; ++d4) {
    int d = d4 * 4;
    float4 x0 = *(const float4*)(xr0 + d);
    float4 x1 = *(const float4*)(xr1 + d);
    float2 w0 = *(float2*)&Wt[d + 0][tx * 2];
    float2 w1 = *(float2*)&Wt[d + 1][tx * 2];
    float2 w2 = *(float2*)&Wt[d + 2][tx * 2];
    float2 w3 = *(float2*)&Wt[d + 3][tx * 2];
#define STEP(XC, WD) \
    acc[0][0] = fmaf(x0.XC, WD.x, acc[0][0]); acc[0][1] = fmaf(x0.XC, WD.y, acc[0][1]); \
    acc[1][0] = fmaf(x1.XC, WD.x, acc[1][0]); acc[1][1] = fmaf(x1.XC, WD.y, acc[1][1]);
    STEP(x, w0) STEP(y, w1) STEP(z, w2) STEP(w, w3)
#undef STEP
  }

#pragma unroll
  for (int i = 0; i < 2; ++i) {
    int row = rowbase + ty * 2 + i;
#pragma unroll
    for (int j = 0; j < 2; ++j) {
      int h = hh + tx * 2 + j;
      P[row * 64 + h] = acc[i][j] * SCALE;
    }
  }
}

// 2048 WGs: wg -> b = wg&7, qi = wg>>3. One q-row per WG; 4 waves strided over
// 64-k tiles (no barriers in main loop; k/V read straight from L2). Online
// softmax per wave; 2-barrier merge of the 4 partials at the end.
__global__ __launch_bounds__(256, 4) void attn_kernel(
    const float* __restrict__ qp, const float* __restrict__ kp,
    const uint16_t* __restrict__ vbf, const float* __restrict__ w_v,
    const int* __restrict__ valid_lens, float* __restrict__ out)
{
  __shared__ float q_lds[64];
  __shared__ float w2_lds[64];
  __shared__ float p_lds[4][64];
  __shared__ float m_s[4], l_s[4];
  __shared__ float oacc[4][64][4];

  const int t = threadIdx.x;
  const int lane = t & 63;
  const int w = t >> 6;
  const int wg = blockIdx.x;
  const int b = wg & 7;
  const int qi = wg >> 3;

  if (t < 64)            q_lds[t] = qp[(b * LQ + qi) * 64 + t];
  else if (t < 128)      w2_lds[t - 64] = -2.f * w_v[t - 64];

  // W1 = sum(w_v) via wave butterfly
  float W1 = w_v[lane];
#pragma unroll
  for (int s = 32; s; s >>= 1) W1 += __shfl_xor(W1, s, 64);

  __syncthreads();

  const int vl = valid_lens[b];
  const int n = (vl > 0) ? vl : LK;   // vl==0 -> all masked -> uniform softmax over all 512
  const int ntiles = (n + 63) >> 6;

  float m = -1e30f, l = 0.f;
  float acc0 = 0.f, acc1 = 0.f, acc2 = 0.f, acc3 = 0.f;

  const float* kpb = kp + (size_t)b * LK * 64;
  const uint16_t* vb = vbf + (size_t)b * LK * 256;

  for (int tile = w; tile < ntiles; tile += 4) {
    const int k0 = tile << 6;

    // ---- scores: lane = kj; k-row read as 16x dwordx4 straight from L2 ----
    const float* krow = kpb + (size_t)(k0 + lane) * 64;
    float r_acc = 0.f;
#pragma unroll
    for (int g = 0; g < 16; ++g) {
      float4 kf = *(const float4*)(krow + g * 4);
      float4 qf = *(const float4*)&q_lds[g * 4];
      float4 wf = *(const float4*)&w2_lds[g * 4];
      r_acc = fmaf(wf.x, frcp(1.f + fexp2(qf.x + kf.x)), r_acc);
      r_acc = fmaf(wf.y, frcp(1.f + fexp2(qf.y + kf.y)), r_acc);
      r_acc = fmaf(wf.z, frcp(1.f + fexp2(qf.z + kf.z)), r_acc);
      r_acc = fmaf(wf.w, frcp(1.f + fexp2(qf.w + kf.w)), r_acc);
    }
    float score;
    int kg = k0 + lane;
    if (vl == 0)      score = 0.f;
    else if (kg < n)  score = W1 + r_acc;
    else              score = -1e30f;

    // ---- online softmax (wave-wide) ----
    float mt = score;
#pragma unroll
    for (int s = 32; s; s >>= 1) mt = fmaxf(mt, __shfl_xor(mt, s, 64));
    float mnew = fmaxf(m, mt);
    float alpha = fexp2((m - mnew) * L2E);
    float p = fexp2((score - mnew) * L2E);
    m = mnew;
    float S = p;
#pragma unroll
    for (int s = 32; s; s >>= 1) S += __shfl_xor(S, s, 64);
    l = l * alpha + S;
    p_lds[w][lane] = p;   // same-wave handoff (compiler inserts lgkmcnt wait)

    // ---- PV: lane = d-chunk (4 contiguous d); V bf16 from L2 ----
    acc0 *= alpha; acc1 *= alpha; acc2 *= alpha; acc3 *= alpha;
    const uint32_t* vt = (const uint32_t*)(vb + (size_t)k0 * 256);
#pragma unroll
    for (int kj4 = 0; kj4 < 16; ++kj4) {
      float4 pv = *(float4*)&p_lds[w][kj4 * 4];
#pragma unroll
      for (int jj = 0; jj < 4; ++jj) {
        int kj = kj4 * 4 + jj;
        uint2 vvv = *(const uint2*)(vt + (size_t)kj * 128 + lane * 2);
        float pj = (jj == 0) ? pv.x : (jj == 1) ? pv.y : (jj == 2) ? pv.z : pv.w;
        float f0 = __uint_as_float(vvv.x << 16);
        float f1 = __uint_as_float(vvv.x & 0xFFFF0000u);
        float f2 = __uint_as_float(vvv.y << 16);
        float f3 = __uint_as_float(vvv.y & 0xFFFF0000u);
        acc0 = fmaf(pj, f0, acc0);
        acc1 = fmaf(pj, f1, acc1);
        acc2 = fmaf(pj, f2, acc2);
        acc3 = fmaf(pj, f3, acc3);
      }
    }
  }

  // ---- merge the 4 waves' partials ----
  if (lane == 0) { m_s[w] = m; l_s[w] = l; }
  __syncthreads();
  float m0 = m_s[0], m1 = m_s[1], m2 = m_s[2], m3 = m_s[3];
  float mstar = fmaxf(fmaxf(m0, m1), fmaxf(m2, m3));
  float sc = fexp2((m - mstar) * L2E);            // wave-uniform
  float lstar = fexp2((m0 - mstar) * L2E) * l_s[0]
              + fexp2((m1 - mstar) * L2E) * l_s[1]
              + fexp2((m2 - mstar) * L2E) * l_s[2]
              + fexp2((m3 - mstar) * L2E) * l_s[3];
  float4 sacc = {acc0 * sc, acc1 * sc, acc2 * sc, acc3 * sc};
  *(float4*)&oacc[w][lane][0] = sacc;
  __syncthreads();
  if (w == 0) {
    float4 a0 = *(float4*)&oacc[0][lane][0];
    float4 a1 = *(float4*)&oacc[1][lane][0];
    float4 a2 = *(float4*)&oacc[2][lane][0];
    float4 a3 = *(float4*)&oacc[3][lane][0];
    float inv = 1.f / lstar;
    float4 o = {(a0.x + a1.x + a2.x + a3.x) * inv,
                (a0.y + a1.y + a2.y + a3.y) * inv,
                (a0.z + a1.z + a2.z + a3.z) * inv,
                (a0.w + a1.w + a2.w + a3.w) * inv};
    *(float4*)(out + (size_t)(b * LQ + qi) * 256 + lane * 4) = o;
  }
}

extern "C" void kernel_launch(void* const* d_in, const int* in_sizes, int n_in,
                              void* d_out, int out_size, void* d_ws, size_t ws_size,
                              hipStream_t stream) {
  const float* queries    = (const float*)d_in[0];
  const float* keys       = (const float*)d_in[1];
  const float* values     = (const float*)d_in[2];
  const int*   valid_lens = (const int*)d_in[3];
  const float* Wq         = (const float*)d_in[4];
  const float* Wk         = (const float*)d_in[5];
  const float* w_v        = (const float*)d_in[6];
  float* out = (float*)d_out;

  float* qp = (float*)d_ws;                     // [2048][64]
  float* kp = qp + QP_ELEMS;                    // [4096][64]
  uint16_t* vbf = (uint16_t*)(kp + KP_ELEMS);   // [8][512][256] bf16

  hipLaunchKernelGGL(proj_kernel, dim3(448), dim3(256), 0, stream,
                     queries, keys, values, Wq, Wk, qp, kp, vbf);
  hipLaunchKernelGGL(attn_kernel, dim3(2048), dim3(256), 0, stream,
                     qp, kp, vbf, w_v, valid_lens, out);
}

// Round 3
// 56.909 us; speedup vs baseline: 2.2120x; 2.2120x over previous
//
#include <hip/hip_runtime.h>
#include <hip/hip_bf16.h>
#include <stdint.h>

#define NB 8
#define LQ 256
#define LK 512
#define NH 64
// 2*log2(e): folded into projections so tanh(x) = 1 - 2/(1+exp2(SCALE*x_sum))
#define SCALE 2.8853900817779268f
#define L2E 1.4426950408889634f

// ws layout (f32 slots)
#define QP_OFF   0            // [2048][64]
#define KPT_OFF  131072       // [8][64][512] transposed k-proj
#define VBF_OFF  393216       // [8][512][256] bf16 (524288 f32 slots)
#define PML_OFF  917504       // [2048][4]  {m0,l0,m1,l1}
#define PACC_OFF 925696       // [2048][2][256]
#define WS_SPLIT_F32 1974272  // floats needed for split mode

extern "C" __device__ float __ocml_exp2_f32(float);
static __device__ __forceinline__ float fexp2(float x) {
#if __has_builtin(__builtin_amdgcn_exp2f)
  return __builtin_amdgcn_exp2f(x);
#else
  return __ocml_exp2_f32(x);
#endif
}
static __device__ __forceinline__ float frcp(float x) {
  return __builtin_amdgcn_rcpf(x);
}
static __device__ __forceinline__ uint16_t f2bf(float f) {
  uint32_t u = __float_as_uint(f);
  uint32_t r = (u + 0x7FFFu + ((u >> 16) & 1u)) >> 16;  // RNE
  return (uint16_t)r;
}

// blocks 0..127:   q-projection  -> qp[row][h]            (scaled)
// blocks 128..383: k-projection  -> kpT[b][h][kj]         (scaled, transposed)
// blocks 384..447: values f32 -> bf16
__global__ __launch_bounds__(256) void proj_kernel(
    const float* __restrict__ queries, const float* __restrict__ keys,
    const float* __restrict__ values,
    const float* __restrict__ Wq, const float* __restrict__ Wk,
    float* __restrict__ qp, float* __restrict__ kpT, uint16_t* __restrict__ vbf)
{
  __shared__ float Wt[256][36];
  const int blk = blockIdx.x;
  const int t = threadIdx.x;

  if (blk >= 384) {
    int base = (blk - 384) * 16384 + t * 4;
#pragma unroll
    for (int it = 0; it < 16; ++it) {
      int idx = base + it * 1024;
      float4 v = *(const float4*)(values + idx);
      uint32_t lo = (uint32_t)f2bf(v.x) | ((uint32_t)f2bf(v.y) << 16);
      uint32_t hi = (uint32_t)f2bf(v.z) | ((uint32_t)f2bf(v.w) << 16);
      uint2 pk = {lo, hi};
      *(uint2*)(vbf + idx) = pk;
    }
    return;
  }

  const bool isQ = (blk < 128);
  const int sub = isQ ? blk : (blk - 128);
  const int tile = sub >> 1;
  const int hh = (sub & 1) * 32;
  const int rowbase = tile * 32;
  const float* __restrict__ X = isQ ? queries : keys;
  const float* __restrict__ W = isQ ? Wq : Wk;

#pragma unroll 4
  for (int it = 0; it < 32; ++it) {
    Wt[t][it] = W[(hh + it) * 256 + t];
  }
  __syncthreads();

  const int ty = t >> 4;          // 0..15 -> 2 rows each
  const int tx = t & 15;          // 0..15 -> 2 h each
  float acc[2][2];
  acc[0][0] = acc[0][1] = acc[1][0] = acc[1][1] = 0.f;

  const float* xr0 = X + (rowbase + ty * 2 + 0) * 256;
  const float* xr1 = X + (rowbase + ty * 2 + 1) * 256;

#pragma unroll 4
  for (int d4 = 0; d4 < 64; ++d4) {
    int d = d4 * 4;
    float4 x0 = *(const float4*)(xr0 + d);
    float4 x1 = *(const float4*)(xr1 + d);
    float2 w0 = *(float2*)&Wt[d + 0][tx * 2];
    float2 w1 = *(float2*)&Wt[d + 1][tx * 2];
    float2 w2 = *(float2*)&Wt[d + 2][tx * 2];
    float2 w3 = *(float2*)&Wt[d + 3][tx * 2];
#define STEP(XC, WD) \
    acc[0][0] = fmaf(x0.XC, WD.x, acc[0][0]); acc[0][1] = fmaf(x0.XC, WD.y, acc[0][1]); \
    acc[1][0] = fmaf(x1.XC, WD.x, acc[1][0]); acc[1][1] = fmaf(x1.XC, WD.y, acc[1][1]);
    STEP(x, w0) STEP(y, w1) STEP(z, w2) STEP(w, w3)
#undef STEP
  }

#pragma unroll
  for (int i = 0; i < 2; ++i) {
    int row = rowbase + ty * 2 + i;
#pragma unroll
    for (int j = 0; j < 2; ++j) {
      int h = hh + tx * 2 + j;
      float val = acc[i][j] * SCALE;
      if (isQ) {
        qp[row * 64 + h] = val;
      } else {
        int b = row >> 9, kj = row & 511;
        kpT[((size_t)(b * 64 + h)) * 512 + kj] = val;
      }
    }
  }
}

// nsplit==2: 1024 WGs, wg -> b=wg&7, kh=(wg>>3)&1, qq=wg>>4; partials to ws.
// nsplit==1: 512 WGs,  wg -> b=wg&7, qq=wg>>3; direct output.
// WG = 4 waves, wave w owns q-row row0+w. Per 64-k tile: register prefetch
// (issued during previous tile's compute) -> linear conflict-free ds_writes ->
// scores (lane=kj) -> wave online softmax -> PV (lane=d-chunk).
__global__ __launch_bounds__(256, 3) void attn_kernel(
    const float* __restrict__ qp, const float* __restrict__ kpT,
    const uint16_t* __restrict__ vbf, const float* __restrict__ w_v,
    const int* __restrict__ valid_lens, float* __restrict__ out,
    float* __restrict__ pml, float* __restrict__ pacc, int nsplit)
{
  __shared__ float kTs[64][64];       // [h][kj] 16KB (score reads 2-way = free)
  __shared__ uint32_t Vs[64][128];    // [kj][d-pair] 32KB (PV b64 reads 2-way)
  __shared__ float q_lds[4][64];
  __shared__ float w2_lds[64];
  __shared__ float p_lds[4][64];

  const int t = threadIdx.x;
  const int lane = t & 63;
  const int w = t >> 6;
  const int wg = blockIdx.x;
  const int b = wg & 7;
  const int kh = (nsplit == 2) ? ((wg >> 3) & 1) : 0;
  const int qq = (nsplit == 2) ? (wg >> 4) : (wg >> 3);
  const int row0 = b * LQ + qq * 4;

  ((float*)q_lds)[t] = qp[(size_t)row0 * 64 + t];   // 4 rows x 64, contiguous
  if (t < 64) w2_lds[t] = -2.f * w_v[t];

  float W1 = w_v[lane];
#pragma unroll
  for (int s = 32; s; s >>= 1) W1 += __shfl_xor(W1, s, 64);

  __syncthreads();

  const int vl = valid_lens[b];
  const int n = (vl > 0) ? vl : LK;     // vl==0 -> uniform softmax over all 512
  const int kstart = kh * 256;
  const int span = (nsplit == 2) ? 256 : 512;
  int cnt = n - kstart;
  if (cnt > span) cnt = span;
  const int ntiles = (cnt > 0) ? ((cnt + 63) >> 6) : 0;

  float m = -1e30f, l = 0.f;
  float acc0 = 0.f, acc1 = 0.f, acc2 = 0.f, acc3 = 0.f;

  const float* kpTb = kpT + (size_t)b * 64 * 512;
  const char* vb = (const char*)(vbf + (size_t)b * LK * 256);

  // register prefetch buffers (fully static indexing)
  float4 kr0, kr1, kr2, kr3;
  uint4 vr0, vr1, vr2, vr3, vr4, vr5, vr6, vr7;

#define PREF(K0) do { \
    const float* ks = kpTb + (size_t)(t >> 4) * 512 + (K0) + (t & 15) * 4; \
    kr0 = *(const float4*)(ks);            \
    kr1 = *(const float4*)(ks + 16 * 512); \
    kr2 = *(const float4*)(ks + 32 * 512); \
    kr3 = *(const float4*)(ks + 48 * 512); \
    const char* vt = vb + (size_t)(K0) * 512 + t * 16; \
    vr0 = *(const uint4*)(vt + 0 * 4096); \
    vr1 = *(const uint4*)(vt + 1 * 4096); \
    vr2 = *(const uint4*)(vt + 2 * 4096); \
    vr3 = *(const uint4*)(vt + 3 * 4096); \
    vr4 = *(const uint4*)(vt + 4 * 4096); \
    vr5 = *(const uint4*)(vt + 5 * 4096); \
    vr6 = *(const uint4*)(vt + 6 * 4096); \
    vr7 = *(const uint4*)(vt + 7 * 4096); \
  } while (0)

  if (ntiles > 0) PREF(kstart);

  for (int tt = 0; tt < ntiles; ++tt) {
    const int k0 = kstart + tt * 64;
    __syncthreads();   // previous tile's LDS readers done
    {  // linear conflict-free ds_writes of the prefetched tile
      float* kd = ((float*)kTs) + t * 4;
      *(float4*)(kd + 0)    = kr0;
      *(float4*)(kd + 1024) = kr1;
      *(float4*)(kd + 2048) = kr2;
      *(float4*)(kd + 3072) = kr3;
      char* vd = ((char*)Vs) + t * 16;
      *(uint4*)(vd + 0 * 4096) = vr0;
      *(uint4*)(vd + 1 * 4096) = vr1;
      *(uint4*)(vd + 2 * 4096) = vr2;
      *(uint4*)(vd + 3 * 4096) = vr3;
      *(uint4*)(vd + 4 * 4096) = vr4;
      *(uint4*)(vd + 5 * 4096) = vr5;
      *(uint4*)(vd + 6 * 4096) = vr6;
      *(uint4*)(vd + 7 * 4096) = vr7;
    }
    if (tt + 1 < ntiles) PREF(k0 + 64);   // hide next tile's load latency under compute
    __syncthreads();   // tile staged

    // ---- scores: lane = kj; 4 independent fma chains ----
    float r0 = 0.f, r1 = 0.f, r2 = 0.f, r3 = 0.f;
#pragma unroll
    for (int g = 0; g < 16; ++g) {
      float4 qf = *(const float4*)&q_lds[w][g * 4];
      float4 wf = *(const float4*)&w2_lds[g * 4];
      float ka = kTs[g * 4 + 0][lane];
      float kb = kTs[g * 4 + 1][lane];
      float kc = kTs[g * 4 + 2][lane];
      float kd = kTs[g * 4 + 3][lane];
      r0 = fmaf(wf.x, frcp(1.f + fexp2(qf.x + ka)), r0);
      r1 = fmaf(wf.y, frcp(1.f + fexp2(qf.y + kb)), r1);
      r2 = fmaf(wf.z, frcp(1.f + fexp2(qf.z + kc)), r2);
      r3 = fmaf(wf.w, frcp(1.f + fexp2(qf.w + kd)), r3);
    }
    float r_acc = (r0 + r1) + (r2 + r3);

    float score;
    int kg = k0 + lane;
    if (vl == 0)      score = 0.f;
    else if (kg < n)  score = W1 + r_acc;
    else              score = -1e30f;

    // ---- online softmax (wave-wide) ----
    float mt = score;
#pragma unroll
    for (int s = 32; s; s >>= 1) mt = fmaxf(mt, __shfl_xor(mt, s, 64));
    float mnew = fmaxf(m, mt);
    float alpha = fexp2((m - mnew) * L2E);
    float p = fexp2((score - mnew) * L2E);
    m = mnew;
    float S = p;
#pragma unroll
    for (int s = 32; s; s >>= 1) S += __shfl_xor(S, s, 64);
    l = l * alpha + S;
    p_lds[w][lane] = p;   // same-wave handoff

    // ---- PV: lane = d-chunk (4 contiguous d) ----
    acc0 *= alpha; acc1 *= alpha; acc2 *= alpha; acc3 *= alpha;
#pragma unroll
    for (int kj4 = 0; kj4 < 16; ++kj4) {
      float4 pv = *(float4*)&p_lds[w][kj4 * 4];
#pragma unroll
      for (int jj = 0; jj < 4; ++jj) {
        int kj = kj4 * 4 + jj;
        uint2 vvv = *(uint2*)&Vs[kj][lane * 2];
        float pj = (jj == 0) ? pv.x : (jj == 1) ? pv.y : (jj == 2) ? pv.z : pv.w;
        float f0 = __uint_as_float(vvv.x << 16);
        float f1 = __uint_as_float(vvv.x & 0xFFFF0000u);
        float f2 = __uint_as_float(vvv.y << 16);
        float f3 = __uint_as_float(vvv.y & 0xFFFF0000u);
        acc0 = fmaf(pj, f0, acc0);
        acc1 = fmaf(pj, f1, acc1);
        acc2 = fmaf(pj, f2, acc2);
        acc3 = fmaf(pj, f3, acc3);
      }
    }
  }
#undef PREF

  const int row = row0 + w;
  if (nsplit == 2) {
    if (lane == 0) { pml[row * 4 + kh * 2] = m; pml[row * 4 + kh * 2 + 1] = l; }
    float4 a = {acc0, acc1, acc2, acc3};
    *(float4*)&pacc[((size_t)row * 2 + kh) * 256 + lane * 4] = a;
  } else {
    float inv = 1.f / l;
    float4 o = {acc0 * inv, acc1 * inv, acc2 * inv, acc3 * inv};
    *(float4*)(out + (size_t)row * 256 + lane * 4) = o;
  }
}

// combine the two k-half partials per q-row. 512 blocks x 256 thr; 4 rows/block.
__global__ __launch_bounds__(256) void merge_kernel(
    const float* __restrict__ pml, const float* __restrict__ pacc,
    float* __restrict__ out)
{
  const int t = threadIdx.x;
  const int row = blockIdx.x * 4 + (t >> 6);
  const int d4 = t & 63;
  float m0 = pml[row * 4 + 0], l0 = pml[row * 4 + 1];
  float m1 = pml[row * 4 + 2], l1 = pml[row * 4 + 3];
  float ms = fmaxf(m0, m1);
  float e0 = fexp2((m0 - ms) * L2E);
  float e1 = fexp2((m1 - ms) * L2E);
  float inv = 1.f / (e0 * l0 + e1 * l1);
  float4 a0 = *(const float4*)&pacc[((size_t)row * 2 + 0) * 256 + d4 * 4];
  float4 a1 = *(const float4*)&pacc[((size_t)row * 2 + 1) * 256 + d4 * 4];
  float4 o = {(a0.x * e0 + a1.x * e1) * inv,
              (a0.y * e0 + a1.y * e1) * inv,
              (a0.z * e0 + a1.z * e1) * inv,
              (a0.w * e0 + a1.w * e1) * inv};
  *(float4*)(out + (size_t)row * 256 + d4 * 4) = o;
}

extern "C" void kernel_launch(void* const* d_in, const int* in_sizes, int n_in,
                              void* d_out, int out_size, void* d_ws, size_t ws_size,
                              hipStream_t stream) {
  const float* queries    = (const float*)d_in[0];
  const float* keys       = (const float*)d_in[1];
  const float* values     = (const float*)d_in[2];
  const int*   valid_lens = (const int*)d_in[3];
  const float* Wq         = (const float*)d_in[4];
  const float* Wk         = (const float*)d_in[5];
  const float* w_v        = (const float*)d_in[6];
  float* out = (float*)d_out;

  float* ws = (float*)d_ws;
  float* qp   = ws + QP_OFF;
  float* kpT  = ws + KPT_OFF;
  uint16_t* vbf = (uint16_t*)(ws + VBF_OFF);
  float* pml  = ws + PML_OFF;
  float* pacc = ws + PACC_OFF;

  const int nsplit = (ws_size >= (size_t)WS_SPLIT_F32 * 4) ? 2 : 1;

  hipLaunchKernelGGL(proj_kernel, dim3(448), dim3(256), 0, stream,
                     queries, keys, values, Wq, Wk, qp, kpT, vbf);
  hipLaunchKernelGGL(attn_kernel, dim3(nsplit == 2 ? 1024 : 512), dim3(256), 0, stream,
                     qp, kpT, vbf, w_v, valid_lens, out, pml, pacc, nsplit);
  if (nsplit == 2) {
    hipLaunchKernelGGL(merge_kernel, dim3(512), dim3(256), 0, stream,
                       pml, pacc, out);
  }
}